// Round 1
// baseline (317.319 us; speedup 1.0000x reference)
//
#include <hip/hip_runtime.h>
#include <hip/hip_bf16.h>
#include <cstdint>

#define SEQ   1024
#define DOUT  1024
#define KDIM  1024
#define MTOT  4096      // BS*SEQ
#define NEXTRA 40       // 8 mw + 32 z cols
#define NPAD  1152      // 9 * 128 N tiles

typedef __bf16 bf16x8 __attribute__((ext_vector_type(8)));
typedef float  f32x4  __attribute__((ext_vector_type(4)));

__device__ inline unsigned short f2bf(float f) {
  union { float f; unsigned u; } a; a.f = f;
  unsigned r = a.u + 0x7fff + ((a.u >> 16) & 1);   // RNE
  return (unsigned short)(r >> 16);
}

__device__ inline void gl16(const void* g, void* l) {
  __builtin_amdgcn_global_load_lds((__attribute__((address_space(1))) void*)g,
                                   (__attribute__((address_space(3))) void*)l, 16, 0, 0);
}

// x (f32) -> bf16, 4 elems/thread, exact grid
__global__ __launch_bounds__(256) void k_cvt_x(const float4* __restrict__ x, ushort4* __restrict__ xb) {
  int i = blockIdx.x * 256 + threadIdx.x;
  float4 v = x[i];
  ushort4 o; o.x = f2bf(v.x); o.y = f2bf(v.y); o.z = f2bf(v.z); o.w = f2bf(v.w);
  xb[i] = o;
}

// Wc rows: [0,1024)=W rows, [1024,1032)=phi^T, [1032,1064)=A2^T (lora_a), [1064,1152)=0
__global__ __launch_bounds__(256) void k_build_wc(const float* __restrict__ W, const float* __restrict__ phi,
                                                  const float* __restrict__ la, unsigned short* __restrict__ Wc) {
  int i = blockIdx.x * 256 + threadIdx.x;      // 1152*1024 exact
  int row = i >> 10, d = i & 1023;
  float v;
  if (row < 1024)       v = W[i];
  else if (row < 1032)  v = phi[d * 8 + (row - 1024)];
  else if (row < 1064)  { int kr = row - 1032; v = la[(kr >> 2) * 4096 + d * 4 + (kr & 3)]; }
  else                  v = 0.f;
  Wc[i] = f2bf(v);
}

// 128x128 tile bf16 GEMM (m97 structure): A[M,K] @ B[N,K]^T, BK=32, 4 waves of 64x64
__global__ __launch_bounds__(256) void k_gemm(const unsigned short* __restrict__ A,
                                              const unsigned short* __restrict__ B,
                                              float* __restrict__ out, float* __restrict__ mwz,
                                              const float* __restrict__ bias) {
  __shared__ unsigned short As[128 * 32];
  __shared__ unsigned short Bs[128 * 32];
  int bm = blockIdx.x, bn = blockIdx.y;
  int t = threadIdx.x;
  int wave = t >> 6, lane = t & 63;
  int wr = wave >> 1, wc = wave & 1;
  int quad = lane >> 4, lr = lane & 15;
  f32x4 acc[4][4];
#pragma unroll
  for (int i = 0; i < 4; i++)
#pragma unroll
    for (int j = 0; j < 4; j++) acc[i][j] = (f32x4){0.f, 0.f, 0.f, 0.f};

  const unsigned short* aG = A + (size_t)bm * 128 * KDIM;
  const unsigned short* bG = B + (size_t)bn * 128 * KDIM;
  int r0 = t >> 2;           // 0..63: tile row
  int c0 = (t & 3) * 8;      // bf16 col offset within BK

  for (int kb = 0; kb < KDIM; kb += 32) {
    __syncthreads();
#pragma unroll
    for (int i = 0; i < 2; ++i) {
      int r = r0 + i * 64;
      // LDS dest: wave-uniform base + lane*16B => row-major [128][32], no pad
      gl16(aG + (size_t)r * KDIM + kb + c0, &As[i * 2048 + wave * 512]);
      gl16(bG + (size_t)r * KDIM + kb + c0, &Bs[i * 2048 + wave * 512]);
    }
    __syncthreads();
    bf16x8 af[4], bfr[4];
#pragma unroll
    for (int mi = 0; mi < 4; mi++) af[mi]  = *(const bf16x8*)&As[(wr * 64 + mi * 16 + lr) * 32 + quad * 8];
#pragma unroll
    for (int ni = 0; ni < 4; ni++) bfr[ni] = *(const bf16x8*)&Bs[(wc * 64 + ni * 16 + lr) * 32 + quad * 8];
#pragma unroll
    for (int mi = 0; mi < 4; mi++)
#pragma unroll
      for (int ni = 0; ni < 4; ni++)
        acc[mi][ni] = __builtin_amdgcn_mfma_f32_16x16x32_bf16(af[mi], bfr[ni], acc[mi][ni], 0, 0, 0);
  }
  // epilogue: C/D layout col=lane&15, row=quad*4+reg
#pragma unroll
  for (int mi = 0; mi < 4; mi++) {
#pragma unroll
    for (int ni = 0; ni < 4; ni++) {
      int col = bn * 128 + wc * 64 + ni * 16 + lr;
#pragma unroll
      for (int rg = 0; rg < 4; ++rg) {
        int row = bm * 128 + wr * 64 + mi * 16 + quad * 4 + rg;
        float v = acc[mi][ni][rg];
        if (col < DOUT)                out[(size_t)row * DOUT + col] = v + bias[col];
        else if (col < DOUT + NEXTRA)  mwz[(size_t)row * NEXTRA + (col - DOUT)] = v;
        // col >= 1064: zero-padded, discard
      }
    }
  }
}

// per-batch: inclusive prefix scans of z*pad (32 cols) + pad count + thresh
__global__ __launch_bounds__(1024) void k_scan(const float* __restrict__ mwz,
                                               const int* __restrict__ inst, const int* __restrict__ pad,
                                               float* __restrict__ T, float* __restrict__ Pc,
                                               int* __restrict__ thr) {
  int b = blockIdx.x;
  int wv = threadIdx.x >> 6, lane = threadIdx.x & 63;
#pragma unroll
  for (int cc = 0; cc < 2; ++cc) {
    int c = wv * 2 + cc;
    float off = 0.f;
    for (int ch = 0; ch < 16; ++ch) {
      int p = ch * 64 + lane;
      float pm = (float)pad[b * SEQ + p];
      float v = mwz[(size_t)(b * SEQ + p) * NEXTRA + 8 + c] * pm;
#pragma unroll
      for (int d = 1; d < 64; d <<= 1) { float o = __shfl_up(v, d); if (lane >= d) v += o; }
      T[(size_t)(b * SEQ + p) * 32 + c] = v + off;
      off += __shfl(v, 63);
    }
  }
  if (wv == 0) {
    float off = 0.f;
    for (int ch = 0; ch < 16; ++ch) {
      int p = ch * 64 + lane;
      float v = (float)pad[b * SEQ + p];
#pragma unroll
      for (int d = 1; d < 64; d <<= 1) { float o = __shfl_up(v, d); if (lane >= d) v += o; }
      Pc[b * SEQ + p] = v + off;
      off += __shfl(v, 63);
    }
  } else if (wv == 1) {
    int fo = 1 << 30, no = 0;
    for (int ch = 0; ch < 16; ++ch) {
      int p = ch * 64 + lane;
      int iv = inst[b * SEQ + p];
      if (iv > 0) fo = min(fo, p);
      no += iv;
    }
#pragma unroll
    for (int d = 1; d < 64; d <<= 1) { fo = min(fo, __shfl_xor(fo, d)); no += __shfl_xor(no, d); }
    if (lane == 0) thr[b] = (no > 0) ? (fo + no) : 0;
  }
}

// per 16 tokens: g = softmax_k(mw) * prefix_mean_z; out += g @ lora_b[32,1024]
__global__ __launch_bounds__(256) void k_adapter(const float* __restrict__ mwz, const float* __restrict__ T,
                                                 const float* __restrict__ Pc, const int* __restrict__ thr,
                                                 const int* __restrict__ pad, const float* __restrict__ B2,
                                                 float* __restrict__ out) {
  __shared__ float g[16][32];
  int blk = blockIdx.x, tid = threadIdx.x;
  if (tid < 16) {
    int q = blk * 16 + tid, b = q >> 10, s = q & 1023;
    if (pad[q] == 0) {
      for (int kr = 0; kr < 32; ++kr) g[tid][kr] = 0.f;
    } else {
      int e = max(thr[b], s + 1) - 1;        // inclusive end index
      float cnt = Pc[b * SEQ + e];
      float C[8], mx = -1e30f;
      for (int k = 0; k < 8; ++k) { C[k] = mwz[(size_t)q * NEXTRA + k]; mx = fmaxf(mx, C[k]); }
      float sm = 0.f;
      for (int k = 0; k < 8; ++k) { C[k] = __expf(C[k] - mx); sm += C[k]; }
      float inv = 1.f / (sm * cnt);
      for (int kr = 0; kr < 32; ++kr)
        g[tid][kr] = C[kr >> 2] * inv * T[(size_t)(b * SEQ + e) * 32 + kr];
    }
  }
  __syncthreads();
#pragma unroll
  for (int oc = 0; oc < 4; ++oc) {
    int o = oc * 256 + tid;
    float br[32];
#pragma unroll
    for (int kr = 0; kr < 32; ++kr) br[kr] = B2[kr * 1024 + o];
#pragma unroll
    for (int idx = 0; idx < 16; ++idx) {
      int q = blk * 16 + idx;
      float s = 0.f;
#pragma unroll
      for (int kr = 0; kr < 32; ++kr) s += g[idx][kr] * br[kr];
      out[(size_t)q * DOUT + o] += s;
    }
  }
}

extern "C" void kernel_launch(void* const* d_in, const int* in_sizes, int n_in,
                              void* d_out, int out_size, void* d_ws, size_t ws_size,
                              hipStream_t stream) {
  const float* x    = (const float*)d_in[0];
  const float* phi  = (const float*)d_in[1];
  const float* la   = (const float*)d_in[2];
  const float* lb   = (const float*)d_in[3];
  const float* W    = (const float*)d_in[4];
  const float* bias = (const float*)d_in[5];
  const int*   inst = (const int*)d_in[6];
  const int*   pad  = (const int*)d_in[7];
  float* out = (float*)d_out;

  char* ws = (char*)d_ws;
  unsigned short* xb = (unsigned short*)ws;                          // 8 MB
  unsigned short* Wc = (unsigned short*)(ws + 8388608);              // 2.25 MB
  float* mwz = (float*)(ws + 8388608 + 2359296);                     // 640 KB
  float* T   = (float*)(ws + 8388608 + 2359296 + 655360);            // 512 KB
  float* Pc  = (float*)(ws + 8388608 + 2359296 + 655360 + 524288);   // 16 KB
  int*   thr = (int*)  (ws + 8388608 + 2359296 + 655360 + 524288 + 16384);

  hipLaunchKernelGGL(k_cvt_x,    dim3(4096),  dim3(256),  0, stream, (const float4*)x, (ushort4*)xb);
  hipLaunchKernelGGL(k_build_wc, dim3(4608),  dim3(256),  0, stream, W, phi, la, Wc);
  hipLaunchKernelGGL(k_gemm,     dim3(32, 9), dim3(256),  0, stream, xb, Wc, out, mwz, bias);
  hipLaunchKernelGGL(k_scan,     dim3(4),     dim3(1024), 0, stream, mwz, inst, pad, T, Pc, thr);
  hipLaunchKernelGGL(k_adapter,  dim3(256),   dim3(256),  0, stream, mwz, T, Pc, thr, pad, lb, out);
}

// Round 2
// 180.357 us; speedup vs baseline: 1.7594x; 1.7594x over previous
//
#include <hip/hip_runtime.h>
#include <hip/hip_bf16.h>
#include <cstdint>

#define SEQ   1024
#define DOUT  1024
#define KDIM  1024
#define MTOT  4096      // BS*SEQ
#define NEXTRA 40       // 8 mw + 32 z cols
#define NPAD  1152      // 9 * 128 N tiles

typedef __bf16 bf16x8 __attribute__((ext_vector_type(8)));
typedef float  f32x4  __attribute__((ext_vector_type(4)));

__device__ inline unsigned short f2bf(float f) {
  union { float f; unsigned u; } a; a.f = f;
  unsigned r = a.u + 0x7fff + ((a.u >> 16) & 1);   // RNE
  return (unsigned short)(r >> 16);
}

__device__ inline void gl16(const void* g, void* l) {
  __builtin_amdgcn_global_load_lds((__attribute__((address_space(1))) void*)g,
                                   (__attribute__((address_space(3))) void*)l, 16, 0, 0);
}

// x (f32) -> bf16, 4 elems/thread, exact grid
__global__ __launch_bounds__(256) void k_cvt_x(const float4* __restrict__ x, ushort4* __restrict__ xb) {
  int i = blockIdx.x * 256 + threadIdx.x;
  float4 v = x[i];
  ushort4 o; o.x = f2bf(v.x); o.y = f2bf(v.y); o.z = f2bf(v.z); o.w = f2bf(v.w);
  xb[i] = o;
}

// Wc rows: [0,1024)=W rows, [1024,1032)=phi^T, [1032,1064)=A2^T (lora_a), [1064,1152)=0
__global__ __launch_bounds__(256) void k_build_wc(const float* __restrict__ W, const float* __restrict__ phi,
                                                  const float* __restrict__ la, unsigned short* __restrict__ Wc) {
  int i = blockIdx.x * 256 + threadIdx.x;      // 1152*1024 exact
  int row = i >> 10, d = i & 1023;
  float v;
  if (row < 1024)       v = W[i];
  else if (row < 1032)  v = phi[d * 8 + (row - 1024)];
  else if (row < 1064)  { int kr = row - 1032; v = la[(kr >> 2) * 4096 + d * 4 + (kr & 3)]; }
  else                  v = 0.f;
  Wc[i] = f2bf(v);
}

// 128x128 tile bf16 GEMM (m97 structure): A[M,K] @ B[N,K]^T, BK=32, 4 waves of 64x64
__global__ __launch_bounds__(256) void k_gemm(const unsigned short* __restrict__ A,
                                              const unsigned short* __restrict__ B,
                                              float* __restrict__ out, float* __restrict__ mwz,
                                              const float* __restrict__ bias) {
  __shared__ unsigned short As[128 * 32];
  __shared__ unsigned short Bs[128 * 32];
  int bm = blockIdx.x, bn = blockIdx.y;
  int t = threadIdx.x;
  int wave = t >> 6, lane = t & 63;
  int wr = wave >> 1, wc = wave & 1;
  int quad = lane >> 4, lr = lane & 15;
  f32x4 acc[4][4];
#pragma unroll
  for (int i = 0; i < 4; i++)
#pragma unroll
    for (int j = 0; j < 4; j++) acc[i][j] = (f32x4){0.f, 0.f, 0.f, 0.f};

  const unsigned short* aG = A + (size_t)bm * 128 * KDIM;
  const unsigned short* bG = B + (size_t)bn * 128 * KDIM;
  int r0 = t >> 2;           // 0..63: tile row
  int c0 = (t & 3) * 8;      // bf16 col offset within BK

  for (int kb = 0; kb < KDIM; kb += 32) {
    __syncthreads();
#pragma unroll
    for (int i = 0; i < 2; ++i) {
      int r = r0 + i * 64;
      // LDS dest: wave-uniform base + lane*16B => row-major [128][32], no pad
      gl16(aG + (size_t)r * KDIM + kb + c0, &As[i * 2048 + wave * 512]);
      gl16(bG + (size_t)r * KDIM + kb + c0, &Bs[i * 2048 + wave * 512]);
    }
    __syncthreads();
    bf16x8 af[4], bfr[4];
#pragma unroll
    for (int mi = 0; mi < 4; mi++) af[mi]  = *(const bf16x8*)&As[(wr * 64 + mi * 16 + lr) * 32 + quad * 8];
#pragma unroll
    for (int ni = 0; ni < 4; ni++) bfr[ni] = *(const bf16x8*)&Bs[(wc * 64 + ni * 16 + lr) * 32 + quad * 8];
#pragma unroll
    for (int mi = 0; mi < 4; mi++)
#pragma unroll
      for (int ni = 0; ni < 4; ni++)
        acc[mi][ni] = __builtin_amdgcn_mfma_f32_16x16x32_bf16(af[mi], bfr[ni], acc[mi][ni], 0, 0, 0);
  }
  // epilogue: C/D layout col=lane&15, row=quad*4+reg
#pragma unroll
  for (int mi = 0; mi < 4; mi++) {
#pragma unroll
    for (int ni = 0; ni < 4; ni++) {
      int col = bn * 128 + wc * 64 + ni * 16 + lr;
#pragma unroll
      for (int rg = 0; rg < 4; ++rg) {
        int row = bm * 128 + wr * 64 + mi * 16 + quad * 4 + rg;
        float v = acc[mi][ni][rg];
        if (col < DOUT)                out[(size_t)row * DOUT + col] = v + bias[col];
        else if (col < DOUT + NEXTRA)  mwz[(size_t)row * NEXTRA + (col - DOUT)] = v;
        // col >= 1064: zero-padded, discard
      }
    }
  }
}

// per-batch: inclusive prefix scans of z*pad (32 cols) + pad count + thresh
__global__ __launch_bounds__(1024) void k_scan(const float* __restrict__ mwz,
                                               const int* __restrict__ inst, const int* __restrict__ pad,
                                               float* __restrict__ T, float* __restrict__ Pc,
                                               int* __restrict__ thr) {
  int b = blockIdx.x;
  int wv = threadIdx.x >> 6, lane = threadIdx.x & 63;
#pragma unroll
  for (int cc = 0; cc < 2; ++cc) {
    int c = wv * 2 + cc;
    float off = 0.f;
    for (int ch = 0; ch < 16; ++ch) {
      int p = ch * 64 + lane;
      float pm = (float)pad[b * SEQ + p];
      float v = mwz[(size_t)(b * SEQ + p) * NEXTRA + 8 + c] * pm;
#pragma unroll
      for (int d = 1; d < 64; d <<= 1) { float o = __shfl_up(v, d); if (lane >= d) v += o; }
      T[(size_t)(b * SEQ + p) * 32 + c] = v + off;
      off += __shfl(v, 63);
    }
  }
  if (wv == 0) {
    float off = 0.f;
    for (int ch = 0; ch < 16; ++ch) {
      int p = ch * 64 + lane;
      float v = (float)pad[b * SEQ + p];
#pragma unroll
      for (int d = 1; d < 64; d <<= 1) { float o = __shfl_up(v, d); if (lane >= d) v += o; }
      Pc[b * SEQ + p] = v + off;
      off += __shfl(v, 63);
    }
  } else if (wv == 1) {
    int fo = 1 << 30, no = 0;
    for (int ch = 0; ch < 16; ++ch) {
      int p = ch * 64 + lane;
      int iv = inst[b * SEQ + p];
      if (iv > 0) fo = min(fo, p);
      no += iv;
    }
#pragma unroll
    for (int d = 1; d < 64; d <<= 1) { fo = min(fo, __shfl_xor(fo, d)); no += __shfl_xor(no, d); }
    if (lane == 0) thr[b] = (no > 0) ? (fo + no) : 0;
  }
}

// per-token gate row: g[q][kr] = softmax_k(mw)[kr/4] * T[e][kr] / (cnt)
__global__ __launch_bounds__(64) void k_gate(const float* __restrict__ mwz, const float* __restrict__ T,
                                             const float* __restrict__ Pc, const int* __restrict__ thr,
                                             const int* __restrict__ pad, float* __restrict__ g) {
  int q = blockIdx.x * 64 + threadIdx.x;   // grid 64 x 64 = 4096 tokens
  int b = q >> 10, s = q & 1023;
  f32x4* gp = (f32x4*)(g + (size_t)q * 32);
  if (pad[q] == 0) {
    f32x4 z = {0.f, 0.f, 0.f, 0.f};
#pragma unroll
    for (int i = 0; i < 8; ++i) gp[i] = z;
    return;
  }
  int e = max(thr[b], s + 1) - 1;          // inclusive end index
  float cnt = Pc[b * SEQ + e];
  float C[8], mx = -1e30f;
#pragma unroll
  for (int k = 0; k < 8; ++k) { C[k] = mwz[(size_t)q * NEXTRA + k]; mx = fmaxf(mx, C[k]); }
  float sm = 0.f;
#pragma unroll
  for (int k = 0; k < 8; ++k) { C[k] = __expf(C[k] - mx); sm += C[k]; }
  float inv = 1.f / (sm * cnt);
  const f32x4* Tp = (const f32x4*)(T + (size_t)(b * SEQ + e) * 32);
#pragma unroll
  for (int i = 0; i < 8; ++i) {            // kr = 4i..4i+3 all share skill k=i
    f32x4 t = Tp[i];
    float w = C[i] * inv;
    gp[i] = (f32x4){t[0] * w, t[1] * w, t[2] * w, t[3] * w};
  }
}

// out[q,o] += sum_kr g[q,kr] * B2[kr,o] — [4096,32]@[32,1024]; g reads are
// wave-uniform -> s_load into SGPRs; B2 column slice + acc[16] in VGPRs.
__global__ __launch_bounds__(256) void k_adapter2(const float* __restrict__ g, const float* __restrict__ B2,
                                                  float* __restrict__ out) {
  int tg = blockIdx.x;                     // 256 groups of 16 tokens
  int o = blockIdx.y * 256 + threadIdx.x;  // 4 col groups
  float br[32];
#pragma unroll
  for (int kr = 0; kr < 32; ++kr) br[kr] = B2[kr * 1024 + o];
  float acc[16];
#pragma unroll
  for (int idx = 0; idx < 16; ++idx) acc[idx] = 0.f;
  const float* gq = g + (size_t)tg * 16 * 32;   // uniform base
#pragma unroll
  for (int idx = 0; idx < 16; ++idx)
#pragma unroll
    for (int kr = 0; kr < 32; ++kr)
      acc[idx] += gq[idx * 32 + kr] * br[kr];   // uniform addr -> s_load
#pragma unroll
  for (int idx = 0; idx < 16; ++idx)
    out[(size_t)(tg * 16 + idx) * DOUT + o] += acc[idx];
}

extern "C" void kernel_launch(void* const* d_in, const int* in_sizes, int n_in,
                              void* d_out, int out_size, void* d_ws, size_t ws_size,
                              hipStream_t stream) {
  const float* x    = (const float*)d_in[0];
  const float* phi  = (const float*)d_in[1];
  const float* la   = (const float*)d_in[2];
  const float* lb   = (const float*)d_in[3];
  const float* W    = (const float*)d_in[4];
  const float* bias = (const float*)d_in[5];
  const int*   inst = (const int*)d_in[6];
  const int*   pad  = (const int*)d_in[7];
  float* out = (float*)d_out;

  char* ws = (char*)d_ws;
  unsigned short* xb = (unsigned short*)ws;                          // 8 MB (dead after k_gemm)
  unsigned short* Wc = (unsigned short*)(ws + 8388608);              // 2.25 MB
  float* mwz = (float*)(ws + 8388608 + 2359296);                     // 640 KB
  float* T   = (float*)(ws + 8388608 + 2359296 + 655360);            // 512 KB
  float* Pc  = (float*)(ws + 8388608 + 2359296 + 655360 + 524288);   // 16 KB
  int*   thr = (int*)  (ws + 8388608 + 2359296 + 655360 + 524288 + 16384);
  float* g   = (float*)ws;                                           // 512 KB, reuses xb region

  hipLaunchKernelGGL(k_cvt_x,    dim3(4096),    dim3(256),  0, stream, (const float4*)x, (ushort4*)xb);
  hipLaunchKernelGGL(k_build_wc, dim3(4608),    dim3(256),  0, stream, W, phi, la, Wc);
  hipLaunchKernelGGL(k_gemm,     dim3(32, 9),   dim3(256),  0, stream, xb, Wc, out, mwz, bias);
  hipLaunchKernelGGL(k_scan,     dim3(4),       dim3(1024), 0, stream, mwz, inst, pad, T, Pc, thr);
  hipLaunchKernelGGL(k_gate,     dim3(64),      dim3(64),   0, stream, mwz, T, Pc, thr, pad, g);
  hipLaunchKernelGGL(k_adapter2, dim3(256, 4),  dim3(256),  0, stream, g, lb, out);
}

// Round 3
// 140.434 us; speedup vs baseline: 2.2596x; 1.2843x over previous
//
#include <hip/hip_runtime.h>
#include <hip/hip_bf16.h>
#include <cstdint>

#define SEQ   1024
#define DOUT  1024
#define KDIM  1024
#define MTOT  4096      // BS*SEQ
#define NEXTRA 40       // 8 mw + 32 z cols
#define NPAD  1152      // 9 * 128 N tiles

typedef __bf16 bf16x8 __attribute__((ext_vector_type(8)));
typedef float  f32x4  __attribute__((ext_vector_type(4)));

__device__ inline unsigned short f2bf(float f) {
  union { float f; unsigned u; } a; a.f = f;
  unsigned r = a.u + 0x7fff + ((a.u >> 16) & 1);   // RNE
  return (unsigned short)(r >> 16);
}

__device__ inline void gl16(const void* g, void* l) {
  __builtin_amdgcn_global_load_lds((__attribute__((address_space(1))) void*)g,
                                   (__attribute__((address_space(3))) void*)l, 16, 0, 0);
}

// x (f32) -> bf16, 4 elems/thread, exact grid
__global__ __launch_bounds__(256) void k_cvt_x(const float4* __restrict__ x, ushort4* __restrict__ xb) {
  int i = blockIdx.x * 256 + threadIdx.x;
  float4 v = x[i];
  ushort4 o; o.x = f2bf(v.x); o.y = f2bf(v.y); o.z = f2bf(v.z); o.w = f2bf(v.w);
  xb[i] = o;
}

// Wc rows: [0,1024)=W rows, [1024,1032)=phi^T, [1032,1064)=A2^T (lora_a), [1064,1152)=0
__global__ __launch_bounds__(256) void k_build_wc(const float* __restrict__ W, const float* __restrict__ phi,
                                                  const float* __restrict__ la, unsigned short* __restrict__ Wc) {
  int i = blockIdx.x * 256 + threadIdx.x;      // 1152*1024 exact
  int row = i >> 10, d = i & 1023;
  float v;
  if (row < 1024)       v = W[i];
  else if (row < 1032)  v = phi[d * 8 + (row - 1024)];
  else if (row < 1064)  { int kr = row - 1032; v = la[(kr >> 2) * 4096 + d * 4 + (kr & 3)]; }
  else                  v = 0.f;
  Wc[i] = f2bf(v);
}

// 128x128 tile bf16 GEMM (m97 structure): A[M,K] @ B[N,K]^T, BK=32, 4 waves of 64x64
__global__ __launch_bounds__(256) void k_gemm(const unsigned short* __restrict__ A,
                                              const unsigned short* __restrict__ B,
                                              float* __restrict__ out, float* __restrict__ mwzT,
                                              const float* __restrict__ bias) {
  __shared__ unsigned short As[128 * 32];
  __shared__ unsigned short Bs[128 * 32];
  int bm = blockIdx.x, bn = blockIdx.y;
  int t = threadIdx.x;
  int wave = t >> 6, lane = t & 63;
  int wr = wave >> 1, wc = wave & 1;
  int quad = lane >> 4, lr = lane & 15;
  f32x4 acc[4][4];
#pragma unroll
  for (int i = 0; i < 4; i++)
#pragma unroll
    for (int j = 0; j < 4; j++) acc[i][j] = (f32x4){0.f, 0.f, 0.f, 0.f};

  const unsigned short* aG = A + (size_t)bm * 128 * KDIM;
  const unsigned short* bG = B + (size_t)bn * 128 * KDIM;
  int r0 = t >> 2;           // 0..63: tile row
  int c0 = (t & 3) * 8;      // bf16 col offset within BK

  for (int kb = 0; kb < KDIM; kb += 32) {
    __syncthreads();
#pragma unroll
    for (int i = 0; i < 2; ++i) {
      int r = r0 + i * 64;
      gl16(aG + (size_t)r * KDIM + kb + c0, &As[i * 2048 + wave * 512]);
      gl16(bG + (size_t)r * KDIM + kb + c0, &Bs[i * 2048 + wave * 512]);
    }
    __syncthreads();
    bf16x8 af[4], bfr[4];
#pragma unroll
    for (int mi = 0; mi < 4; mi++) af[mi]  = *(const bf16x8*)&As[(wr * 64 + mi * 16 + lr) * 32 + quad * 8];
#pragma unroll
    for (int ni = 0; ni < 4; ni++) bfr[ni] = *(const bf16x8*)&Bs[(wc * 64 + ni * 16 + lr) * 32 + quad * 8];
#pragma unroll
    for (int mi = 0; mi < 4; mi++)
#pragma unroll
      for (int ni = 0; ni < 4; ni++)
        acc[mi][ni] = __builtin_amdgcn_mfma_f32_16x16x32_bf16(af[mi], bfr[ni], acc[mi][ni], 0, 0, 0);
  }
  // epilogue: C/D layout col=lane&15, row=quad*4+reg
#pragma unroll
  for (int mi = 0; mi < 4; mi++) {
#pragma unroll
    for (int ni = 0; ni < 4; ni++) {
      int col = bn * 128 + wc * 64 + ni * 16 + lr;
#pragma unroll
      for (int rg = 0; rg < 4; ++rg) {
        int row = bm * 128 + wr * 64 + mi * 16 + quad * 4 + rg;
        float v = acc[mi][ni][rg];
        if (col < DOUT)                out[(size_t)row * DOUT + col] = v + bias[col];
        else if (col < DOUT + NEXTRA)  mwzT[(size_t)(col - DOUT) * MTOT + row] = v;  // transposed
      }
    }
  }
}

// block (b,c): single-pass 1024-elem scan. c in [0,32): T cols; c==32: Pc; c==33: thr
__global__ __launch_bounds__(1024) void k_scan(const float* __restrict__ mwzT,
                                               const int* __restrict__ inst, const int* __restrict__ pad,
                                               float* __restrict__ T, float* __restrict__ Pc,
                                               int* __restrict__ thr) {
  int b = blockIdx.x, c = blockIdx.y;
  int tid = threadIdx.x;
  int wv = tid >> 6, lane = tid & 63;
  __shared__ float ws[16];
  __shared__ int fos[16], nos[16];

  if (c == 33) {
    int iv = inst[b * SEQ + tid];
    int fo = iv ? tid : (1 << 30);
    int no = iv;
#pragma unroll
    for (int d = 1; d < 64; d <<= 1) { fo = min(fo, __shfl_xor(fo, d)); no += __shfl_xor(no, d); }
    if (lane == 0) { fos[wv] = fo; nos[wv] = no; }
    __syncthreads();
    if (tid == 0) {
      int F = 1 << 30, N = 0;
#pragma unroll
      for (int i = 0; i < 16; ++i) { F = min(F, fos[i]); N += nos[i]; }
      thr[b] = (N > 0) ? F + N : 0;
    }
    return;
  }

  float pm = (float)pad[b * SEQ + tid];
  float v = (c < 32) ? mwzT[(size_t)c * MTOT + b * SEQ + tid] * pm : pm;
#pragma unroll
  for (int d = 1; d < 64; d <<= 1) { float o = __shfl_up(v, d); if (lane >= d) v += o; }
  if (lane == 63) ws[wv] = v;
  __syncthreads();
  if (wv == 0 && lane < 16) {
    float orig = ws[lane], s = orig;
#pragma unroll
    for (int d = 1; d < 16; d <<= 1) { float o = __shfl_up(s, d); if (lane >= d) s += o; }
    ws[lane] = s - orig;                 // exclusive offset for wave `lane`
  }
  __syncthreads();
  v += ws[wv];
  if (c < 32) T[(size_t)c * MTOT + b * SEQ + tid] = v;
  else        Pc[b * SEQ + tid] = v;
}

// per-token gate row: g[q][kr] = softmax_k(mw)[kr/4] * T[kr][e] / cnt
__global__ __launch_bounds__(64) void k_gate(const float* __restrict__ mwzT, const float* __restrict__ T,
                                             const float* __restrict__ Pc, const int* __restrict__ thr,
                                             const int* __restrict__ pad, float* __restrict__ g) {
  int q = blockIdx.x * 64 + threadIdx.x;   // 64 x 64 = 4096 tokens
  int b = q >> 10, s = q & 1023;
  float* gp = g + (size_t)q * 32;
  if (pad[q] == 0) {
#pragma unroll
    for (int i = 0; i < 32; ++i) gp[i] = 0.f;
    return;
  }
  int e = max(thr[b], s + 1) - 1;          // inclusive end index
  int e0 = b * SEQ + e;
  float cnt = Pc[e0];
  float C[8], mx = -1e30f;
#pragma unroll
  for (int k = 0; k < 8; ++k) { C[k] = mwzT[(size_t)k * MTOT + q]; mx = fmaxf(mx, C[k]); }
  float sm = 0.f;
#pragma unroll
  for (int k = 0; k < 8; ++k) { C[k] = __expf(C[k] - mx); sm += C[k]; }
  float inv = 1.f / (sm * cnt);
#pragma unroll
  for (int kr = 0; kr < 32; ++kr)
    gp[kr] = C[kr >> 2] * inv * T[(size_t)kr * MTOT + e0];
}

// out[q,o] += sum_kr g[q,kr] * B2[kr,o] — [4096,32]@[32,1024]; g reads are
// wave-uniform -> s_load into SGPRs; B2 column slice + acc[16] in VGPRs.
__global__ __launch_bounds__(256) void k_adapter2(const float* __restrict__ g, const float* __restrict__ B2,
                                                  float* __restrict__ out) {
  int tg = blockIdx.x;                     // 256 groups of 16 tokens
  int o = blockIdx.y * 256 + threadIdx.x;  // 4 col groups
  float br[32];
#pragma unroll
  for (int kr = 0; kr < 32; ++kr) br[kr] = B2[kr * 1024 + o];
  float acc[16];
#pragma unroll
  for (int idx = 0; idx < 16; ++idx) acc[idx] = 0.f;
  const float* gq = g + (size_t)tg * 16 * 32;   // uniform base
#pragma unroll
  for (int idx = 0; idx < 16; ++idx)
#pragma unroll
    for (int kr = 0; kr < 32; ++kr)
      acc[idx] += gq[idx * 32 + kr] * br[kr];   // uniform addr -> s_load
#pragma unroll
  for (int idx = 0; idx < 16; ++idx)
    out[(size_t)(tg * 16 + idx) * DOUT + o] += acc[idx];
}

extern "C" void kernel_launch(void* const* d_in, const int* in_sizes, int n_in,
                              void* d_out, int out_size, void* d_ws, size_t ws_size,
                              hipStream_t stream) {
  const float* x    = (const float*)d_in[0];
  const float* phi  = (const float*)d_in[1];
  const float* la   = (const float*)d_in[2];
  const float* lb   = (const float*)d_in[3];
  const float* W    = (const float*)d_in[4];
  const float* bias = (const float*)d_in[5];
  const int*   inst = (const int*)d_in[6];
  const int*   pad  = (const int*)d_in[7];
  float* out = (float*)d_out;

  char* ws = (char*)d_ws;
  unsigned short* xb = (unsigned short*)ws;                          // 8 MB (dead after k_gemm)
  unsigned short* Wc = (unsigned short*)(ws + 8388608);              // 2.25 MB
  float* mwzT = (float*)(ws + 8388608 + 2359296);                    // 640 KB [40][4096]
  float* T    = (float*)(ws + 8388608 + 2359296 + 655360);           // 512 KB [32][4096]
  float* Pc   = (float*)(ws + 8388608 + 2359296 + 655360 + 524288);  // 16 KB
  int*   thr  = (int*)  (ws + 8388608 + 2359296 + 655360 + 524288 + 16384);
  float* g    = (float*)ws;                                          // 512 KB, reuses xb region

  hipLaunchKernelGGL(k_cvt_x,    dim3(4096),    dim3(256),  0, stream, (const float4*)x, (ushort4*)xb);
  hipLaunchKernelGGL(k_build_wc, dim3(4608),    dim3(256),  0, stream, W, phi, la, Wc);
  hipLaunchKernelGGL(k_gemm,     dim3(32, 9),   dim3(256),  0, stream, xb, Wc, out, mwzT, bias);
  hipLaunchKernelGGL(k_scan,     dim3(4, 34),   dim3(1024), 0, stream, mwzT, inst, pad, T, Pc, thr);
  hipLaunchKernelGGL(k_gate,     dim3(64),      dim3(64),   0, stream, mwzT, T, Pc, thr, pad, g);
  hipLaunchKernelGGL(k_adapter2, dim3(256, 4),  dim3(256),  0, stream, g, lb, out);
}

// Round 4
// 125.262 us; speedup vs baseline: 2.5332x; 1.1211x over previous
//
#include <hip/hip_runtime.h>
#include <hip/hip_bf16.h>
#include <cstdint>

#define SEQ   1024
#define DOUT  1024
#define KDIM  1024
#define MTOT  4096      // BS*SEQ
#define WCROWS 1104     // 1024 W + 8 phi + 32 A2 + 8 zero + 32 B2

typedef __bf16 bf16x8 __attribute__((ext_vector_type(8)));
typedef float  f32x4  __attribute__((ext_vector_type(4)));

__device__ inline unsigned short f2bf(float f) {
  union { float f; unsigned u; } a; a.f = f;
  unsigned r = a.u + 0x7fff + ((a.u >> 16) & 1);   // RNE
  return (unsigned short)(r >> 16);
}

__device__ inline void gl16(const void* g, void* l) {
  __builtin_amdgcn_global_load_lds((__attribute__((address_space(1))) void*)g,
                                   (__attribute__((address_space(3))) void*)l, 16, 0, 0);
}

// x (f32) -> bf16, 4 elems/thread, exact grid
__global__ __launch_bounds__(256) void k_cvt_x(const float4* __restrict__ x, ushort4* __restrict__ xb) {
  int i = blockIdx.x * 256 + threadIdx.x;
  float4 v = x[i];
  ushort4 o; o.x = f2bf(v.x); o.y = f2bf(v.y); o.z = f2bf(v.z); o.w = f2bf(v.w);
  xb[i] = o;
}

// Wc rows: [0,1024)=W, [1024,1032)=phi^T, [1032,1064)=A2^T, [1064,1072)=0, [1072,1104)=B2
__global__ __launch_bounds__(256) void k_build_wc(const float* __restrict__ W, const float* __restrict__ phi,
                                                  const float* __restrict__ la, const float* __restrict__ lb,
                                                  unsigned short* __restrict__ Wc) {
  int i = blockIdx.x * 256 + threadIdx.x;      // WCROWS*1024 exact
  int row = i >> 10, d = i & 1023;
  float v;
  if (row < 1024)       v = W[i];
  else if (row < 1032)  v = phi[d * 8 + (row - 1024)];
  else if (row < 1064)  { int kr = row - 1032; v = la[(kr >> 2) * 4096 + d * 4 + (kr & 3)]; }
  else if (row < 1072)  v = 0.f;
  else                  v = lb[(row - 1072) * 1024 + d];   // B2[kr][d]
  Wc[i] = f2bf(v);
}

// thin GEMM: mwzT[c][row] = (x @ [phi|A2])[row][c], c<40. 64 blocks of 64 rows x 48 cols.
__global__ __launch_bounds__(256) void k_mwz(const unsigned short* __restrict__ xb,
                                             const unsigned short* __restrict__ Wc,
                                             float* __restrict__ mwzT) {
  __shared__ unsigned short As[64 * 32];
  __shared__ unsigned short Bs[48 * 32];
  int bm = blockIdx.x;
  int t = threadIdx.x, wave = t >> 6, lane = t & 63;
  int quad = lane >> 4, lr = lane & 15;
  f32x4 acc[3];
#pragma unroll
  for (int i = 0; i < 3; ++i) acc[i] = (f32x4){0.f, 0.f, 0.f, 0.f};
  const unsigned short* aG = xb + (size_t)bm * 64 * KDIM;
  const unsigned short* bG = Wc + (size_t)1024 * KDIM;
  int r0 = t >> 2, c0 = (t & 3) * 8;
  for (int kb = 0; kb < KDIM; kb += 32) {
    __syncthreads();
    gl16(aG + (size_t)r0 * KDIM + kb + c0, &As[wave * 512]);
    if (t < 192) gl16(bG + (size_t)r0 * KDIM + kb + c0, &Bs[wave * 512]);
    __syncthreads();
    bf16x8 af = *(const bf16x8*)&As[(wave * 16 + lr) * 32 + quad * 8];
#pragma unroll
    for (int ni = 0; ni < 3; ++ni) {
      bf16x8 bfr = *(const bf16x8*)&Bs[(ni * 16 + lr) * 32 + quad * 8];
      acc[ni] = __builtin_amdgcn_mfma_f32_16x16x32_bf16(af, bfr, acc[ni], 0, 0, 0);
    }
  }
#pragma unroll
  for (int ni = 0; ni < 3; ++ni) {
    int c = ni * 16 + lr;
#pragma unroll
    for (int rg = 0; rg < 4; ++rg) {
      int row = bm * 64 + wave * 16 + quad * 4 + rg;
      if (c < 40) mwzT[(size_t)c * MTOT + row] = acc[ni][rg];
    }
  }
}

// block (b,c): single-pass 1024-elem scan. c in [0,32): z cols (mwzT rows 8+c); c==32: Pc; c==33: thr
__global__ __launch_bounds__(1024) void k_scan(const float* __restrict__ mwzT,
                                               const int* __restrict__ inst, const int* __restrict__ pad,
                                               float* __restrict__ T, float* __restrict__ Pc,
                                               int* __restrict__ thr) {
  int b = blockIdx.x, c = blockIdx.y;
  int tid = threadIdx.x;
  int wv = tid >> 6, lane = tid & 63;
  __shared__ float ws[16];
  __shared__ int fos[16], nos[16];

  if (c == 33) {
    int iv = inst[b * SEQ + tid];
    int fo = iv ? tid : (1 << 30);
    int no = iv;
#pragma unroll
    for (int d = 1; d < 64; d <<= 1) { fo = min(fo, __shfl_xor(fo, d)); no += __shfl_xor(no, d); }
    if (lane == 0) { fos[wv] = fo; nos[wv] = no; }
    __syncthreads();
    if (tid == 0) {
      int F = 1 << 30, N = 0;
#pragma unroll
      for (int i = 0; i < 16; ++i) { F = min(F, fos[i]); N += nos[i]; }
      thr[b] = (N > 0) ? F + N : 0;
    }
    return;
  }

  float pm = (float)pad[b * SEQ + tid];
  float v = (c < 32) ? mwzT[(size_t)(8 + c) * MTOT + b * SEQ + tid] * pm : pm;  // z cols = rows 8..39
#pragma unroll
  for (int d = 1; d < 64; d <<= 1) { float o = __shfl_up(v, d); if (lane >= d) v += o; }
  if (lane == 63) ws[wv] = v;
  __syncthreads();
  if (wv == 0 && lane < 16) {
    float orig = ws[lane], s = orig;
#pragma unroll
    for (int d = 1; d < 16; d <<= 1) { float o = __shfl_up(s, d); if (lane >= d) s += o; }
    ws[lane] = s - orig;                 // exclusive offset for wave `lane`
  }
  __syncthreads();
  v += ws[wv];
  if (c < 32) T[(size_t)c * MTOT + b * SEQ + tid] = v;
  else        Pc[b * SEQ + tid] = v;
}

// per-token gate row (bf16): g[q][kr] = softmax_k(mw)[kr/4] * T[kr][e] / cnt
__global__ __launch_bounds__(64) void k_gate(const float* __restrict__ mwzT, const float* __restrict__ T,
                                             const float* __restrict__ Pc, const int* __restrict__ thr,
                                             const int* __restrict__ pad, unsigned short* __restrict__ gb) {
  int q = blockIdx.x * 64 + threadIdx.x;   // 64 x 64 = 4096 tokens
  int b = q >> 10, s = q & 1023;
  unsigned short* gp = gb + (size_t)q * 32;
  if (pad[q] == 0) {
    uint4 z4 = {0u, 0u, 0u, 0u};
#pragma unroll
    for (int i = 0; i < 4; ++i) ((uint4*)gp)[i] = z4;
    return;
  }
  int e = max(thr[b], s + 1) - 1;          // inclusive end index
  int e0 = b * SEQ + e;
  float cnt = Pc[e0];
  float C[8], mx = -1e30f;
#pragma unroll
  for (int k = 0; k < 8; ++k) { C[k] = mwzT[(size_t)k * MTOT + q]; mx = fmaxf(mx, C[k]); }
  float sm = 0.f;
#pragma unroll
  for (int k = 0; k < 8; ++k) { C[k] = __expf(C[k] - mx); sm += C[k]; }
  float inv = 1.f / (sm * cnt);
#pragma unroll
  for (int kr = 0; kr < 32; ++kr)
    gp[kr] = f2bf(C[kr >> 2] * inv * T[(size_t)kr * MTOT + e0]);
}

// BM=128 x BN=64 GEMM, 512 blocks (2/CU): out = x@W^T + bias + g@B2 (adapter fused
// as one extra 16x16x32 MFMA K-step from LDS-staged bf16 g-tile and B2-slice).
__global__ __launch_bounds__(256) void k_gemm(const unsigned short* __restrict__ A,
                                              const unsigned short* __restrict__ Wc,
                                              const unsigned short* __restrict__ gb,
                                              float* __restrict__ out,
                                              const float* __restrict__ bias) {
  __shared__ unsigned short As[128 * 32];  // 8 KB; epilogue: g-tile [128][32]
  __shared__ unsigned short Bs[64 * 32];   // 4 KB; epilogue: B2 slice [32][64]
  int bm = blockIdx.x, bn = blockIdx.y;
  int t = threadIdx.x;
  int wave = t >> 6, lane = t & 63;
  int wr = wave >> 1, wc = wave & 1;       // wave: 64 rows x 32 cols
  int quad = lane >> 4, lr = lane & 15;
  f32x4 acc[4][2];
#pragma unroll
  for (int i = 0; i < 4; i++)
#pragma unroll
    for (int j = 0; j < 2; j++) acc[i][j] = (f32x4){0.f, 0.f, 0.f, 0.f};

  const unsigned short* aG = A + (size_t)bm * 128 * KDIM;
  const unsigned short* bG = Wc + (size_t)bn * 64 * KDIM;
  int r0 = t >> 2, c0 = (t & 3) * 8;

  for (int kb = 0; kb < KDIM; kb += 32) {
    __syncthreads();
    gl16(aG + (size_t)r0 * KDIM + kb + c0, &As[wave * 512]);
    gl16(aG + (size_t)(r0 + 64) * KDIM + kb + c0, &As[2048 + wave * 512]);
    gl16(bG + (size_t)r0 * KDIM + kb + c0, &Bs[wave * 512]);
    __syncthreads();
    bf16x8 af[4], bfr[2];
#pragma unroll
    for (int mi = 0; mi < 4; mi++) af[mi]  = *(const bf16x8*)&As[(wr * 64 + mi * 16 + lr) * 32 + quad * 8];
#pragma unroll
    for (int ni = 0; ni < 2; ni++) bfr[ni] = *(const bf16x8*)&Bs[(wc * 32 + ni * 16 + lr) * 32 + quad * 8];
#pragma unroll
    for (int mi = 0; mi < 4; mi++)
#pragma unroll
      for (int ni = 0; ni < 2; ni++)
        acc[mi][ni] = __builtin_amdgcn_mfma_f32_16x16x32_bf16(af[mi], bfr[ni], acc[mi][ni], 0, 0, 0);
  }

  // ---- fused adapter: stage g-tile + B2 slice, one MFMA K-step ----
  __syncthreads();
  gl16(gb + (size_t)(bm * 128 + r0) * 32 + c0,        &As[wave * 512]);
  gl16(gb + (size_t)(bm * 128 + 64 + r0) * 32 + c0,   &As[2048 + wave * 512]);
  {
    int kr = t >> 3, co = (t & 7) * 8;
    uint4 v = *(const uint4*)(Wc + (size_t)(1072 + kr) * KDIM + bn * 64 + co);
    *(uint4*)&Bs[kr * 64 + co] = v;
  }
  __syncthreads();
  bf16x8 af2[4];
#pragma unroll
  for (int mi = 0; mi < 4; mi++) af2[mi] = *(const bf16x8*)&As[(wr * 64 + mi * 16 + lr) * 32 + quad * 8];
#pragma unroll
  for (int ni = 0; ni < 2; ni++) {
    union { bf16x8 v; unsigned short u[8]; } bu;
    int col = wc * 32 + ni * 16 + lr;
#pragma unroll
    for (int j = 0; j < 8; ++j) bu.u[j] = Bs[(quad * 8 + j) * 64 + col];
#pragma unroll
    for (int mi = 0; mi < 4; mi++)
      acc[mi][ni] = __builtin_amdgcn_mfma_f32_16x16x32_bf16(af2[mi], bu.v, acc[mi][ni], 0, 0, 0);
  }

  // ---- epilogue: C/D layout col=lane&15, row=quad*4+reg ----
#pragma unroll
  for (int mi = 0; mi < 4; mi++) {
#pragma unroll
    for (int ni = 0; ni < 2; ni++) {
      int col = bn * 64 + wc * 32 + ni * 16 + lr;
      float bv = bias[col];
#pragma unroll
      for (int rg = 0; rg < 4; ++rg) {
        int row = bm * 128 + wr * 64 + mi * 16 + quad * 4 + rg;
        out[(size_t)row * DOUT + col] = acc[mi][ni][rg] + bv;
      }
    }
  }
}

extern "C" void kernel_launch(void* const* d_in, const int* in_sizes, int n_in,
                              void* d_out, int out_size, void* d_ws, size_t ws_size,
                              hipStream_t stream) {
  const float* x    = (const float*)d_in[0];
  const float* phi  = (const float*)d_in[1];
  const float* la   = (const float*)d_in[2];
  const float* lb   = (const float*)d_in[3];
  const float* W    = (const float*)d_in[4];
  const float* bias = (const float*)d_in[5];
  const int*   inst = (const int*)d_in[6];
  const int*   pad  = (const int*)d_in[7];
  float* out = (float*)d_out;

  char* ws = (char*)d_ws;
  unsigned short* xb  = (unsigned short*)ws;                   // 8 MB
  unsigned short* Wc  = (unsigned short*)(ws + 8388608);       // WCROWS*1024*2 = 2.16 MB (reserve 2.25)
  float* mwzT = (float*)(ws + 10747904);                       // [40][4096] f32, 640 KB
  float* T    = (float*)(ws + 11403264);                       // [32][4096] f32, 512 KB
  float* Pc   = (float*)(ws + 11927552);                       // 16 KB
  int*   thr  = (int*)  (ws + 11943936);                       // 4 KB
  unsigned short* gb = (unsigned short*)(ws + 11948032);       // [4096][32] bf16, 256 KB

  hipLaunchKernelGGL(k_cvt_x,    dim3(4096),   dim3(256),  0, stream, (const float4*)x, (ushort4*)xb);
  hipLaunchKernelGGL(k_build_wc, dim3(4416),   dim3(256),  0, stream, W, phi, la, lb, Wc);
  hipLaunchKernelGGL(k_mwz,      dim3(64),     dim3(256),  0, stream, xb, Wc, mwzT);
  hipLaunchKernelGGL(k_scan,     dim3(4, 34),  dim3(1024), 0, stream, mwzT, inst, pad, T, Pc, thr);
  hipLaunchKernelGGL(k_gate,     dim3(64),     dim3(64),   0, stream, mwzT, T, Pc, thr, pad, gb);
  hipLaunchKernelGGL(k_gemm,     dim3(32, 16), dim3(256),  0, stream, xb, Wc, gb, out, bias);
}

// Round 5
// 116.705 us; speedup vs baseline: 2.7190x; 1.0733x over previous
//
#include <hip/hip_runtime.h>
#include <hip/hip_bf16.h>
#include <cstdint>

#define SEQ   1024
#define DOUT  1024
#define KDIM  1024
#define MTOT  4096      // BS*SEQ
#define WCROWS 1104     // 1024 W + 8 phi + 32 A2 + 8 zero + 32 B2

typedef __bf16 bf16x8 __attribute__((ext_vector_type(8)));
typedef float  f32x4  __attribute__((ext_vector_type(4)));

__device__ inline unsigned short f2bf(float f) {
  union { float f; unsigned u; } a; a.f = f;
  unsigned r = a.u + 0x7fff + ((a.u >> 16) & 1);   // RNE
  return (unsigned short)(r >> 16);
}

__device__ inline void gl16(const void* g, void* l) {
  __builtin_amdgcn_global_load_lds((__attribute__((address_space(1))) void*)g,
                                   (__attribute__((address_space(3))) void*)l, 16, 0, 0);
}

// fused prologue: blocks [0,4096) cvt x->bf16; [4096,8512) build Wc; 8512 = thr
__global__ __launch_bounds__(256) void k_prep(const float4* __restrict__ x, ushort4* __restrict__ xb,
                                              const float* __restrict__ W, const float* __restrict__ phi,
                                              const float* __restrict__ la, const float* __restrict__ lb,
                                              unsigned short* __restrict__ Wc,
                                              const int* __restrict__ inst, int* __restrict__ thr) {
  int blk = blockIdx.x, tid = threadIdx.x;
  if (blk < 4096) {
    int i = blk * 256 + tid;
    float4 v = x[i];
    ushort4 o; o.x = f2bf(v.x); o.y = f2bf(v.y); o.z = f2bf(v.z); o.w = f2bf(v.w);
    xb[i] = o;
  } else if (blk < 8512) {
    int i = (blk - 4096) * 256 + tid;            // WCROWS*1024 exact
    int row = i >> 10, d = i & 1023;
    float v;
    if (row < 1024)       v = W[i];
    else if (row < 1032)  v = phi[d * 8 + (row - 1024)];
    else if (row < 1064)  { int kr = row - 1032; v = la[(kr >> 2) * 4096 + d * 4 + (kr & 3)]; }
    else if (row < 1072)  v = 0.f;
    else                  v = lb[(row - 1072) * 1024 + d];   // B2[kr][d]
    Wc[i] = f2bf(v);
  } else {
    int b = tid >> 6, lane = tid & 63;           // wave b handles batch b
    int fo = 1 << 30, no = 0;
#pragma unroll
    for (int j = 0; j < 16; ++j) {
      int p = j * 64 + lane;
      int iv = inst[b * SEQ + p];
      if (iv > 0) fo = min(fo, p);
      no += iv;
    }
#pragma unroll
    for (int d = 1; d < 64; d <<= 1) { fo = min(fo, __shfl_xor(fo, d)); no += __shfl_xor(no, d); }
    if (lane == 0) thr[b] = (no > 0) ? fo + no : 0;
  }
}

// thin GEMM, 4-way K-split: mwzP[ks][c][row] = (x @ [phi|A2])[row][c] over K-quarter ks
__global__ __launch_bounds__(256) void k_mwz(const unsigned short* __restrict__ xb,
                                             const unsigned short* __restrict__ Wc,
                                             float* __restrict__ mwzP) {
  __shared__ unsigned short As[64 * 32];
  __shared__ unsigned short Bs[48 * 32];
  int bm = blockIdx.x, ks = blockIdx.y;
  int t = threadIdx.x, wave = t >> 6, lane = t & 63;
  int quad = lane >> 4, lr = lane & 15;
  f32x4 acc[3];
#pragma unroll
  for (int i = 0; i < 3; ++i) acc[i] = (f32x4){0.f, 0.f, 0.f, 0.f};
  const unsigned short* aG = xb + (size_t)bm * 64 * KDIM + ks * 256;
  const unsigned short* bG = Wc + (size_t)1024 * KDIM + ks * 256;
  int r0 = t >> 2, c0 = (t & 3) * 8;
  for (int kb = 0; kb < 256; kb += 32) {
    __syncthreads();
    gl16(aG + (size_t)r0 * KDIM + kb + c0, &As[wave * 512]);
    if (t < 192) gl16(bG + (size_t)r0 * KDIM + kb + c0, &Bs[wave * 512]);
    __syncthreads();
    bf16x8 af = *(const bf16x8*)&As[(wave * 16 + lr) * 32 + quad * 8];
#pragma unroll
    for (int ni = 0; ni < 3; ++ni) {
      bf16x8 bfr = *(const bf16x8*)&Bs[(ni * 16 + lr) * 32 + quad * 8];
      acc[ni] = __builtin_amdgcn_mfma_f32_16x16x32_bf16(af, bfr, acc[ni], 0, 0, 0);
    }
  }
#pragma unroll
  for (int ni = 0; ni < 3; ++ni) {
    int c = ni * 16 + lr;
#pragma unroll
    for (int rg = 0; rg < 4; ++rg) {
      int row = bm * 64 + wave * 16 + quad * 4 + rg;
      if (c < 40) mwzP[(size_t)(ks * 40 + c) * MTOT + row] = acc[ni][rg];
    }
  }
}

// fused scan+gate: block (b,c): scan z_c*pad and pad over s, then
// gb[q][c] = softmax_k(mw)[c/4] * Tv / cnt   (Tv,cnt at e = max(thr,s+1)-1:
// own position if s+1>=thr, else the single shared position thr-1)
__global__ __launch_bounds__(1024) void k_scan_gate(const float* __restrict__ mwzP,
                                                    const int* __restrict__ pad, const int* __restrict__ thr,
                                                    unsigned short* __restrict__ gb) {
  int b = blockIdx.x, c = blockIdx.y;
  int tid = threadIdx.x, wv = tid >> 6, lane = tid & 63;
  __shared__ float wsz[16], wsp[16];
  __shared__ float sv, spc;
  int q = b * SEQ + tid;
  float pm = (float)pad[q];
  float z = 0.f;
#pragma unroll
  for (int s = 0; s < 4; ++s) z += mwzP[(size_t)(s * 40 + 8 + c) * MTOT + q];
  z *= pm;
  float vz = z, vp = pm;
#pragma unroll
  for (int d = 1; d < 64; d <<= 1) {
    float oz = __shfl_up(vz, d), op = __shfl_up(vp, d);
    if (lane >= d) { vz += oz; vp += op; }
  }
  if (lane == 63) { wsz[wv] = vz; wsp[wv] = vp; }
  __syncthreads();
  if (wv == 0 && lane < 16) {
    float oz = wsz[lane], op = wsp[lane], sz = oz, sp = op;
#pragma unroll
    for (int d = 1; d < 16; d <<= 1) {
      float tz = __shfl_up(sz, d), tp = __shfl_up(sp, d);
      if (lane >= d) { sz += tz; sp += tp; }
    }
    wsz[lane] = sz - oz; wsp[lane] = sp - op;   // exclusive wave offsets
  }
  __syncthreads();
  vz += wsz[wv]; vp += wsp[wv];
  int th = thr[b];
  if (th > 0 && tid == th - 1) { sv = vz; spc = vp; }
  __syncthreads();
  unsigned short o = 0;
  if (pm != 0.f) {
    bool own = (tid + 1 >= th);
    float Tv  = own ? vz : sv;
    float cnt = own ? vp : spc;
    float C[8], mx = -1e30f;
#pragma unroll
    for (int k = 0; k < 8; ++k) {
      float m = 0.f;
#pragma unroll
      for (int s = 0; s < 4; ++s) m += mwzP[(size_t)(s * 40 + k) * MTOT + q];
      C[k] = m; mx = fmaxf(mx, m);
    }
    float sm = 0.f;
#pragma unroll
    for (int k = 0; k < 8; ++k) { C[k] = __expf(C[k] - mx); sm += C[k]; }
    o = f2bf(C[c >> 2] * Tv / (sm * cnt));
  }
  gb[(size_t)q * 32 + c] = o;
}

// BM=128 x BN=64 GEMM, 512 blocks (2/CU): out = x@W^T + bias + g@B2 (adapter fused
// as one extra 16x16x32 MFMA K-step from LDS-staged bf16 g-tile and B2-slice).
__global__ __launch_bounds__(256) void k_gemm(const unsigned short* __restrict__ A,
                                              const unsigned short* __restrict__ Wc,
                                              const unsigned short* __restrict__ gb,
                                              float* __restrict__ out,
                                              const float* __restrict__ bias) {
  __shared__ unsigned short As[128 * 32];  // 8 KB; epilogue: g-tile [128][32]
  __shared__ unsigned short Bs[64 * 32];   // 4 KB; epilogue: B2 slice [32][64]
  int bm = blockIdx.x, bn = blockIdx.y;
  int t = threadIdx.x;
  int wave = t >> 6, lane = t & 63;
  int wr = wave >> 1, wc = wave & 1;       // wave: 64 rows x 32 cols
  int quad = lane >> 4, lr = lane & 15;
  f32x4 acc[4][2];
#pragma unroll
  for (int i = 0; i < 4; i++)
#pragma unroll
    for (int j = 0; j < 2; j++) acc[i][j] = (f32x4){0.f, 0.f, 0.f, 0.f};

  const unsigned short* aG = A + (size_t)bm * 128 * KDIM;
  const unsigned short* bG = Wc + (size_t)bn * 64 * KDIM;
  int r0 = t >> 2, c0 = (t & 3) * 8;

  for (int kb = 0; kb < KDIM; kb += 32) {
    __syncthreads();
    gl16(aG + (size_t)r0 * KDIM + kb + c0, &As[wave * 512]);
    gl16(aG + (size_t)(r0 + 64) * KDIM + kb + c0, &As[2048 + wave * 512]);
    gl16(bG + (size_t)r0 * KDIM + kb + c0, &Bs[wave * 512]);
    __syncthreads();
    bf16x8 af[4], bfr[2];
#pragma unroll
    for (int mi = 0; mi < 4; mi++) af[mi]  = *(const bf16x8*)&As[(wr * 64 + mi * 16 + lr) * 32 + quad * 8];
#pragma unroll
    for (int ni = 0; ni < 2; ni++) bfr[ni] = *(const bf16x8*)&Bs[(wc * 32 + ni * 16 + lr) * 32 + quad * 8];
#pragma unroll
    for (int mi = 0; mi < 4; mi++)
#pragma unroll
      for (int ni = 0; ni < 2; ni++)
        acc[mi][ni] = __builtin_amdgcn_mfma_f32_16x16x32_bf16(af[mi], bfr[ni], acc[mi][ni], 0, 0, 0);
  }

  // ---- fused adapter: stage g-tile + B2 slice, one MFMA K-step ----
  __syncthreads();
  gl16(gb + (size_t)(bm * 128 + r0) * 32 + c0,        &As[wave * 512]);
  gl16(gb + (size_t)(bm * 128 + 64 + r0) * 32 + c0,   &As[2048 + wave * 512]);
  {
    int kr = t >> 3, co = (t & 7) * 8;
    uint4 v = *(const uint4*)(Wc + (size_t)(1072 + kr) * KDIM + bn * 64 + co);
    *(uint4*)&Bs[kr * 64 + co] = v;
  }
  __syncthreads();
  bf16x8 af2[4];
#pragma unroll
  for (int mi = 0; mi < 4; mi++) af2[mi] = *(const bf16x8*)&As[(wr * 64 + mi * 16 + lr) * 32 + quad * 8];
#pragma unroll
  for (int ni = 0; ni < 2; ni++) {
    union { bf16x8 v; unsigned short u[8]; } bu;
    int col = wc * 32 + ni * 16 + lr;
#pragma unroll
    for (int j = 0; j < 8; ++j) bu.u[j] = Bs[(quad * 8 + j) * 64 + col];
#pragma unroll
    for (int mi = 0; mi < 4; mi++)
      acc[mi][ni] = __builtin_amdgcn_mfma_f32_16x16x32_bf16(af2[mi], bu.v, acc[mi][ni], 0, 0, 0);
  }

  // ---- epilogue: C/D layout col=lane&15, row=quad*4+reg ----
#pragma unroll
  for (int mi = 0; mi < 4; mi++) {
#pragma unroll
    for (int ni = 0; ni < 2; ni++) {
      int col = bn * 64 + wc * 32 + ni * 16 + lr;
      float bv = bias[col];
#pragma unroll
      for (int rg = 0; rg < 4; ++rg) {
        int row = bm * 128 + wr * 64 + mi * 16 + quad * 4 + rg;
        out[(size_t)row * DOUT + col] = acc[mi][ni][rg] + bv;
      }
    }
  }
}

extern "C" void kernel_launch(void* const* d_in, const int* in_sizes, int n_in,
                              void* d_out, int out_size, void* d_ws, size_t ws_size,
                              hipStream_t stream) {
  const float* x    = (const float*)d_in[0];
  const float* phi  = (const float*)d_in[1];
  const float* la   = (const float*)d_in[2];
  const float* lb   = (const float*)d_in[3];
  const float* W    = (const float*)d_in[4];
  const float* bias = (const float*)d_in[5];
  const int*   inst = (const int*)d_in[6];
  const int*   pad  = (const int*)d_in[7];
  float* out = (float*)d_out;

  char* ws = (char*)d_ws;
  unsigned short* xb  = (unsigned short*)ws;                   // 8 MB
  unsigned short* Wc  = (unsigned short*)(ws + 8388608);       // 1104*1024*2 = 2260992 B
  float* mwzP = (float*)(ws + 10649600);                       // [4][40][4096] f32 = 2621440 B
  unsigned short* gb = (unsigned short*)(ws + 13271040);       // [4096][32] bf16 = 262144 B
  int*   thr  = (int*)(ws + 13533184);                         // 16 B

  hipLaunchKernelGGL(k_prep,      dim3(8513),   dim3(256),  0, stream,
                     (const float4*)x, (ushort4*)xb, W, phi, la, lb, Wc, inst, thr);
  hipLaunchKernelGGL(k_mwz,       dim3(64, 4),  dim3(256),  0, stream, xb, Wc, mwzP);
  hipLaunchKernelGGL(k_scan_gate, dim3(4, 32),  dim3(1024), 0, stream, mwzP, pad, thr, gb);
  hipLaunchKernelGGL(k_gemm,      dim3(32, 16), dim3(256),  0, stream, xb, Wc, gb, out, bias);
}